// Round 3
// baseline (151.663 us; speedup 1.0000x reference)
//
#include <hip/hip_runtime.h>
#include <math.h>

// ---- problem constants ----
#define Btok 2048
#define Dm   768
#define NE   8
#define Hh   3072
#define OBROWS 5120

typedef short short8 __attribute__((ext_vector_type(8)));
typedef float f32x4  __attribute__((ext_vector_type(4)));

__device__ __forceinline__ short f2bf(float f) {
    unsigned u = __builtin_bit_cast(unsigned, f);
    u += 0x7fffu + ((u >> 16) & 1u);   // round-to-nearest-even
    return (short)(u >> 16);
}

__device__ __forceinline__ float gelu_exact(float v) {
    return 0.5f * v * (1.0f + erff(v * 0.70710678118654752440f));
}

// async global->LDS, 16B per lane; LDS dest = uniform base + lane*16
#define GLDS(gsrc, ldst)                                                           \
    __builtin_amdgcn_global_load_lds(                                              \
        (const __attribute__((address_space(1))) void*)(gsrc),                     \
        (__attribute__((address_space(3))) void*)(ldst),                           \
        16, 0, 0)

// ---------------- logits body: top-2 per token, gates, x->bf16 ----------------
__device__ __forceinline__ void logits_body(const float* __restrict__ x,
                                            const float* __restrict__ wg,
                                            int* __restrict__ t2e,
                                            float* __restrict__ tokgate,
                                            unsigned short* __restrict__ xb,
                                            int b) {
    int wv   = threadIdx.x >> 6;
    int lane = threadIdx.x & 63;
    int tok  = b * 4 + wv;

    const float* xr = x + (size_t)tok * Dm;
    float xv[12];
#pragma unroll
    for (int i = 0; i < 12; ++i) xv[i] = xr[lane + i * 64];

    unsigned short* xw = xb + (size_t)tok * Dm;
#pragma unroll
    for (int i = 0; i < 12; ++i) xw[lane + i * 64] = (unsigned short)f2bf(xv[i]);

    float acc[NE];
#pragma unroll
    for (int e = 0; e < NE; ++e) acc[e] = 0.f;
#pragma unroll
    for (int i = 0; i < 12; ++i) {
        int d = lane + i * 64;
#pragma unroll
        for (int e = 0; e < NE; ++e) acc[e] += xv[i] * wg[d * NE + e];
    }
#pragma unroll
    for (int e = 0; e < NE; ++e) {
#pragma unroll
        for (int off = 32; off > 0; off >>= 1) acc[e] += __shfl_xor(acc[e], off);
    }

    if (lane == 0) {
        int i0 = 0; float v0 = acc[0];
#pragma unroll
        for (int e = 1; e < NE; ++e) { if (acc[e] > v0) { v0 = acc[e]; i0 = e; } }
        int i1 = -1; float v1 = -1e30f;
#pragma unroll
        for (int e = 0; e < NE; ++e) {
            if (e == i0) continue;
            if (acc[e] > v1) { v1 = acc[e]; i1 = e; }
        }
        float tt = __expf(v1 - v0);
        float g0 = 1.0f / (1.0f + tt);
        float g1 = 1.0f - g0;

        t2e[tok * 2 + 0]     = i0;
        t2e[tok * 2 + 1]     = i1;
        tokgate[tok * 2 + 0] = g0;
        tokgate[tok * 2 + 1] = g1;
    }
}

// ---------------- transpose body: fp32 [K][N] -> bf16 [N][K], 64x64 tile (256 thr) ----------------
__device__ __forceinline__ void transpose_body(float (*tile)[65],
                                               const float* __restrict__ in,
                                               unsigned short* __restrict__ out,
                                               int ldIn, int ldOut,
                                               size_t eStrideIn, size_t eStrideOut,
                                               int rowOff, int colOff,
                                               int bx, int by, int bz) {
    const float* src = in + (size_t)bz * eStrideIn
                     + (size_t)(rowOff + by * 64) * ldIn + colOff + bx * 64;
    unsigned short* dst = out + (size_t)bz * eStrideOut
                        + (size_t)(bx * 64) * ldOut + by * 64;
    int t = threadIdx.x;
    int r = t >> 4, c4 = (t & 15) * 4;
#pragma unroll
    for (int it = 0; it < 4; ++it) {
        float4 v = *(const float4*)(src + (size_t)(it * 16 + r) * ldIn + c4);
        tile[it * 16 + r][c4 + 0] = v.x;
        tile[it * 16 + r][c4 + 1] = v.y;
        tile[it * 16 + r][c4 + 2] = v.z;
        tile[it * 16 + r][c4 + 3] = v.w;
    }
    __syncthreads();
#pragma unroll
    for (int it = 0; it < 4; ++it) {
        int n = it * 16 + r;
        unsigned short o0 = (unsigned short)f2bf(tile[c4 + 0][n]);
        unsigned short o1 = (unsigned short)f2bf(tile[c4 + 1][n]);
        unsigned short o2 = (unsigned short)f2bf(tile[c4 + 2][n]);
        unsigned short o3 = (unsigned short)f2bf(tile[c4 + 3][n]);
        uint2 o;
        o.x = (unsigned)o0 | ((unsigned)o1 << 16);
        o.y = (unsigned)o2 | ((unsigned)o3 << 16);
        *(uint2*)(dst + (size_t)n * ldOut + c4) = o;
    }
}

// ---------------- transpose body for 1024-thread blocks: 1 ld / 1 st per thread ----------------
__device__ __forceinline__ void transpose_body_1k(float (*tile)[65],
                                                  const float* __restrict__ in,
                                                  unsigned short* __restrict__ out,
                                                  int ldIn, int ldOut,
                                                  size_t eStrideIn, size_t eStrideOut,
                                                  int rowOff, int colOff,
                                                  int bx, int by, int bz) {
    const float* src = in + (size_t)bz * eStrideIn
                     + (size_t)(rowOff + by * 64) * ldIn + colOff + bx * 64;
    unsigned short* dst = out + (size_t)bz * eStrideOut
                        + (size_t)(bx * 64) * ldOut + by * 64;
    int t = threadIdx.x;
    int r = t >> 4, c4 = (t & 15) * 4;
    float4 v = *(const float4*)(src + (size_t)r * ldIn + c4);
    tile[r][c4 + 0] = v.x;
    tile[r][c4 + 1] = v.y;
    tile[r][c4 + 2] = v.z;
    tile[r][c4 + 3] = v.w;
    __syncthreads();
    unsigned short o0 = (unsigned short)f2bf(tile[c4 + 0][r]);
    unsigned short o1 = (unsigned short)f2bf(tile[c4 + 1][r]);
    unsigned short o2 = (unsigned short)f2bf(tile[c4 + 2][r]);
    unsigned short o3 = (unsigned short)f2bf(tile[c4 + 3][r]);
    uint2 o;
    o.x = (unsigned)o0 | ((unsigned)o1 << 16);
    o.y = (unsigned)o2 | ((unsigned)o3 << 16);
    *(uint2*)(dst + (size_t)r * ldOut + c4) = o;
}

// standalone transpose (used for chunks c>0 when workspace is small)
__global__ __launch_bounds__(256)
void transpose_kernel(const float* __restrict__ in, unsigned short* __restrict__ out,
                      int ldIn, int ldOut, size_t eStrideIn, size_t eStrideOut,
                      int rowOff, int colOff) {
    __shared__ float tile[64][65];
    transpose_body(tile, in, out, ldIn, ldOut, eStrideIn, eStrideOut, rowOff, colOff,
                   blockIdx.x, blockIdx.y, blockIdx.z);
}

// ---------------- prep: blocks 0..511 = logits; rest = W1 transpose (chunk 0) ----------------
__global__ __launch_bounds__(256)
void prep_kernel(const float* __restrict__ x,
                 const float* __restrict__ wg,
                 int* __restrict__ t2e,
                 float* __restrict__ tokgate,
                 unsigned short* __restrict__ xb,
                 const float* __restrict__ W1, unsigned short* __restrict__ w1t,
                 int Hc, int colBase) {
    __shared__ float tile[64][65];
    int b = blockIdx.x;
    const int NL = Btok / 4;                 // 512 logits blocks

    if (b < NL) {
        logits_body(x, wg, t2e, tokgate, xb, b);
    } else {
        // W1 [e][d=768][h] -> w1t [e][h-local][d]
        int nx1 = Hc / 64, ny1 = Dm / 64;
        int q  = b - NL;
        int bx = q % nx1; q /= nx1;
        int by = q % ny1;
        int bz = q / ny1;
        transpose_body(tile, W1, w1t, Hh, Dm, (size_t)Dm * Hh, (size_t)Hc * Dm,
                       0, colBase, bx, by, bz);
    }
}

// ---------------- assign: block 0 = slots/offsets/loss/pad; blocks >0 = W2T tiles ----------------
__global__ __launch_bounds__(1024)
void assign_kernel(const int* __restrict__ t2e,
                   const float* __restrict__ tokgate,
                   int* __restrict__ padded,
                   int* __restrict__ offsets,
                   int* __restrict__ list,
                   int* __restrict__ tokes,
                   float* __restrict__ loss_out,
                   const float* __restrict__ W2,
                   unsigned short* __restrict__ w2t,
                   int Hc) {
    __shared__ int   scnt[NE];
    __shared__ int   spad[NE];
    __shared__ float simp[NE];
    __shared__ float tile[64][65];

    if (blockIdx.x > 0) {
        // W2 [e][h][d=768] -> w2t [e][d][h-local], chunk 0, tiles [0, nTa)
        int ti = blockIdx.x - 1;
        int nx2 = Dm / 64, ny2 = Hc / 64;
        int bx = ti % nx2; int q = ti / nx2;
        int by = q % ny2;
        int bz = q / ny2;
        transpose_body_1k(tile, W2, w2t, Dm, Hc, (size_t)Hh * Dm, (size_t)Dm * Hc,
                          0, 0, bx, by, bz);
        return;
    }

    int tid = threadIdx.x;
    if (tid < NE) { scnt[tid] = 0; simp[tid] = 0.f; }
    __syncthreads();

#pragma unroll
    for (int it = 0; it < Btok / 1024; ++it) {
        int tok = tid + it * 1024;
        int e0 = t2e[tok * 2], e1 = t2e[tok * 2 + 1];
        float g0 = tokgate[tok * 2], g1 = tokgate[tok * 2 + 1];
        int s0 = atomicAdd(&scnt[e0], 1);
        int s1 = atomicAdd(&scnt[e1], 1);
        list[e0 * Btok + s0] = tok;
        list[e1 * Btok + s1] = tok;
        tokes[tok * 2 + 0] = (e0 << 13) | s0;
        tokes[tok * 2 + 1] = (e1 << 13) | s1;
        atomicAdd(&simp[e0], g0);
        atomicAdd(&simp[e1], g1);
    }
    __syncthreads();

    if (tid == 0) {
        int off = 0;
        for (int e = 0; e < NE; ++e) {
            int p = (scnt[e] + 127) & ~127;
            spad[e]    = p;
            padded[e]  = p;
            offsets[e] = off;
            off += p;
        }
        float mi = 0.f, ml = 0.f;
        for (int e = 0; e < NE; ++e) { mi += simp[e]; ml += (float)scnt[e]; }
        mi *= (1.0f / NE); ml *= (1.0f / NE);
        float vi = 0.f, vl = 0.f;
        for (int e = 0; e < NE; ++e) {
            float di = simp[e] - mi;        vi += di * di;
            float dl = (float)scnt[e] - ml; vl += dl * dl;
        }
        vi /= (NE - 1); vl /= (NE - 1);
        loss_out[0] = 1e-2f * (vi / (mi * mi + 1e-10f) + vl / (ml * ml + 1e-10f));
    }
    __syncthreads();

    for (int e = 0; e < NE; ++e) {
        int c = scnt[e], p = spad[e];
        for (int s = c + tid; s < p; s += 1024) list[e * Btok + s] = 0;
    }
}

// ---------------- GEMM1 (+fused W2 transpose, Bresenham-interleaved block IDs) ----------------
__global__ __launch_bounds__(256)
void gemm1_kernel(const unsigned short* __restrict__ xb,
                  const unsigned short* __restrict__ w1t,  // [e][Hc][Dm] bf16
                  const float* __restrict__ b1,
                  const int* __restrict__ list,
                  const int* __restrict__ padded,
                  const int* __restrict__ offsets,
                  unsigned short* __restrict__ hbuf,       // [rows][Hc] bf16
                  int Hc, int colBase, int nG1, int nTr, int tixBase,
                  const float* __restrict__ W2,            // fused W2 transpose (chunk 0)
                  unsigned short* __restrict__ w2t) {
    __shared__ union __align__(16) {
        struct { unsigned short As[2][4096]; unsigned short Bs[2][4096]; } g;
        float tile[64][65];
    } sm;

    int b = blockIdx.x;
    int gid;
    if (nTr > 0) {
        int total = nG1 + nTr;
        int tc  = (int)(((long long)b * nTr) / total);
        int tc1 = (int)(((long long)(b + 1) * nTr) / total);
        if (tc1 != tc) {
            // W2 [e][h][d=768] -> w2t [e][d][h-local], chunk 0
            int tix = tixBase + tc;
            int nx2 = Dm / 64, ny2 = Hc / 64;
            int bx = tix % nx2; int q = tix / nx2;
            int by = q % ny2;
            int bz = q / ny2;
            transpose_body(sm.tile, W2, w2t, Dm, Hc, (size_t)Hh * Dm, (size_t)Dm * Hc,
                           0, 0, bx, by, bz);
            return;
        }
        gid = b - tc;
    } else {
        gid = b;
    }

    int NTQ = Hc / 128;
    int nt = gid % NTQ;
    int mt = (gid / NTQ) % 16;
    int e  = gid / (NTQ * 16);
    if (mt * 128 >= padded[e]) return;
    int roff = offsets[e];

    int t = threadIdx.x, w = t >> 6, lane = t & 63;
    int lr = lane & 15, lh = lane >> 4;
    int wr = (w >> 1) * 64, wc = (w & 1) * 64;
    int r0 = t >> 2;
    int ce = ((t & 3) ^ ((r0 >> 1) & 3)) * 8;   // pre-swizzled global k-chunk
    int ks = (lh ^ ((lr >> 1) & 3)) * 8;        // swizzled read k-chunk

    const int* lst = list + e * Btok + mt * 128;
    int tok0 = lst[r0], tok1 = lst[64 + r0];
    const unsigned short* pa0 = xb + (size_t)tok0 * Dm + ce;
    const unsigned short* pa1 = xb + (size_t)tok1 * Dm + ce;
    const unsigned short* wbp = w1t + ((size_t)e * Hc + (size_t)nt * 128) * Dm;
    const unsigned short* pb0 = wbp + (size_t)r0 * Dm + ce;
    const unsigned short* pb1 = wbp + (size_t)(64 + r0) * Dm + ce;

    int s0 = __builtin_amdgcn_readfirstlane(w * 1024);

    f32x4 acc[4][4];
#pragma unroll
    for (int i = 0; i < 4; ++i)
#pragma unroll
        for (int j = 0; j < 4; ++j) acc[i][j] = (f32x4){0.f, 0.f, 0.f, 0.f};

    auto stage = [&](int buf, int kb) {
        GLDS(pa0 + kb, (char*)&sm.g.As[buf][0] + s0);
        GLDS(pa1 + kb, (char*)&sm.g.As[buf][0] + s0 + 4096);
        GLDS(pb0 + kb, (char*)&sm.g.Bs[buf][0] + s0);
        GLDS(pb1 + kb, (char*)&sm.g.Bs[buf][0] + s0 + 4096);
    };
    auto compute = [&](int buf) {
        short8 a[4], bq[4];
#pragma unroll
        for (int i = 0; i < 4; ++i) a[i] = *(const short8*)&sm.g.As[buf][(wr + i * 16 + lr) * 32 + ks];
#pragma unroll
        for (int j = 0; j < 4; ++j) bq[j] = *(const short8*)&sm.g.Bs[buf][(wc + j * 16 + lr) * 32 + ks];
#pragma unroll
        for (int i = 0; i < 4; ++i)
#pragma unroll
            for (int j = 0; j < 4; ++j)
                acc[i][j] = __builtin_amdgcn_mfma_f32_16x16x32_bf16(a[i], bq[j], acc[i][j], 0, 0, 0);
    };

    const int NTK = Dm / 32;                       // 24
    stage(0, 0);
    __syncthreads();
    int cur = 0;
    for (int kt = 0; kt < NTK; ++kt) {
        if (kt + 1 < NTK) stage(cur ^ 1, (kt + 1) * 32);
        compute(cur);
        __syncthreads();
        cur ^= 1;
    }

    float bj[4];
#pragma unroll
    for (int j = 0; j < 4; ++j)
        bj[j] = b1[(size_t)e * Hh + colBase + nt * 128 + wc + j * 16 + lr];
#pragma unroll
    for (int i = 0; i < 4; ++i) {
#pragma unroll
        for (int j = 0; j < 4; ++j) {
#pragma unroll
            for (int r = 0; r < 4; ++r) {
                int row = wr + i * 16 + lh * 4 + r;
                float v = acc[i][j][r] + bj[j];
                v = gelu_exact(v);
                hbuf[(size_t)(roff + mt * 128 + row) * Hc + nt * 128 + wc + j * 16 + lr]
                    = (unsigned short)f2bf(v);
            }
        }
    }
}

// ---------------- GEMM2: obuf[sk] = h_rows @ W2t^T ----------------
// N-tile = 64 (was 128): doubles live blocks (~400 -> ~790, 1.5 -> 3.1 blocks/CU)
// to fix the latency-bound low-occupancy profile. B-panel reuse across mt is
// unchanged; extra hbuf A-panel re-reads are L3 hits (hbuf ~26MB << 256MB L3).
// id = (((sk*12 + nt)*MT + mt) << 3) | e
__global__ __launch_bounds__(256)
void gemm2_kernel(const unsigned short* __restrict__ hbuf,
                  const unsigned short* __restrict__ w2t,  // [e][Dm][Hc] bf16
                  const int* __restrict__ padded,
                  const int* __restrict__ offsets,
                  float* __restrict__ obuf,                // [2][OBROWS][Dm] fp32
                  int Hc, int MT, int accum) {
    int id = blockIdx.x;
    int e  = id & 7;
    int rr = id >> 3;
    int mt = rr % MT; rr /= MT;
    int nt = rr % 12;
    int sk = rr / 12;
    if (mt * 128 >= padded[e]) return;
    int roff = offsets[e];
    int Kc = Hc >> 1, K0 = sk * Kc;

    __shared__ unsigned short As[2][4096];
    __shared__ unsigned short Bs[2][2048];

    int t = threadIdx.x, w = t >> 6, lane = t & 63;
    int lr = lane & 15, lh = lane >> 4;
    int wr = (w >> 1) * 64, wc = (w & 1) * 32;   // wave tile 64x32
    int r0 = t >> 2;
    int ce = ((t & 3) ^ ((r0 >> 1) & 3)) * 8;
    int ks = (lh ^ ((lr >> 1) & 3)) * 8;

    const unsigned short* ab  = hbuf + (size_t)(roff + mt * 128) * Hc + K0;
    const unsigned short* pa0 = ab + (size_t)r0 * Hc + ce;
    const unsigned short* pa1 = ab + (size_t)(64 + r0) * Hc + ce;
    const unsigned short* wbp = w2t + ((size_t)e * Dm + (size_t)nt * 64) * Hc + K0;
    const unsigned short* pb0 = wbp + (size_t)r0 * Hc + ce;   // 64 rows

    int s0 = __builtin_amdgcn_readfirstlane(w * 1024);

    f32x4 acc[4][2];
#pragma unroll
    for (int i = 0; i < 4; ++i)
#pragma unroll
        for (int j = 0; j < 2; ++j) acc[i][j] = (f32x4){0.f, 0.f, 0.f, 0.f};

    auto stage = [&](int buf, int kb) {
        GLDS(pa0 + kb, (char*)&As[buf][0] + s0);
        GLDS(pa1 + kb, (char*)&As[buf][0] + s0 + 4096);
        GLDS(pb0 + kb, (char*)&Bs[buf][0] + s0);
    };
    auto compute = [&](int buf) {
        short8 a[4], bq[2];
#pragma unroll
        for (int i = 0; i < 4; ++i) a[i] = *(const short8*)&As[buf][(wr + i * 16 + lr) * 32 + ks];
#pragma unroll
        for (int j = 0; j < 2; ++j) bq[j] = *(const short8*)&Bs[buf][(wc + j * 16 + lr) * 32 + ks];
#pragma unroll
        for (int i = 0; i < 4; ++i)
#pragma unroll
            for (int j = 0; j < 2; ++j)
                acc[i][j] = __builtin_amdgcn_mfma_f32_16x16x32_bf16(a[i], bq[j], acc[i][j], 0, 0, 0);
    };

    const int NTK = Kc / 32;
    stage(0, 0);
    __syncthreads();
    int cur = 0;
    for (int kt = 0; kt < NTK; ++kt) {
        if (kt + 1 < NTK) stage(cur ^ 1, (kt + 1) * 32);
        compute(cur);
        __syncthreads();
        cur ^= 1;
    }

    float* orow = obuf + (size_t)sk * OBROWS * Dm
                + (size_t)(roff + mt * 128) * Dm + nt * 64;
#pragma unroll
    for (int i = 0; i < 4; ++i) {
#pragma unroll
        for (int r = 0; r < 4; ++r) {
            int row = wr + i * 16 + lh * 4 + r;
#pragma unroll
            for (int j = 0; j < 2; ++j) {
                int col = wc + j * 16 + lr;
                float v = acc[i][j][r];
                if (accum) v += orow[(size_t)row * Dm + col];
                orow[(size_t)row * Dm + col] = v;
            }
        }
    }
}

// ---------------- combine: y[tok] = sum_j g_j * (partials + b2[e_j]) ----------------
__global__ __launch_bounds__(256)
void combine_kernel(const float* __restrict__ obuf,
                    const int* __restrict__ offsets,
                    const int* __restrict__ tokes,
                    const float* __restrict__ tokgate,
                    const float* __restrict__ b2,
                    float* __restrict__ y) {
    int wv = threadIdx.x >> 6, lane = threadIdx.x & 63;
    int tok = blockIdx.x * 4 + wv;
    int p0 = tokes[tok * 2], p1 = tokes[tok * 2 + 1];
    float g0 = tokgate[tok * 2], g1 = tokgate[tok * 2 + 1];
    int e0 = p0 >> 13, ss0 = p0 & 8191;
    int e1 = p1 >> 13, ss1 = p1 & 8191;
    size_t r0 = (size_t)(offsets[e0] + ss0) * Dm;
    size_t r1 = (size_t)(offsets[e1] + ss1) * Dm;
    const size_t SLAB = (size_t)OBROWS * Dm;
#pragma unroll
    for (int i = 0; i < 3; ++i) {
        int col = (lane + i * 64) * 4;
        float4 a0 = *(const float4*)(obuf + r0 + col);
        float4 a1 = *(const float4*)(obuf + SLAB + r0 + col);
        float4 c0 = *(const float4*)(obuf + r1 + col);
        float4 c1 = *(const float4*)(obuf + SLAB + r1 + col);
        float4 be0 = *(const float4*)(b2 + (size_t)e0 * Dm + col);
        float4 be1 = *(const float4*)(b2 + (size_t)e1 * Dm + col);
        float4 o;
        o.x = g0 * (a0.x + a1.x + be0.x) + g1 * (c0.x + c1.x + be1.x);
        o.y = g0 * (a0.y + a1.y + be0.y) + g1 * (c0.y + c1.y + be1.y);
        o.z = g0 * (a0.z + a1.z + be0.z) + g1 * (c0.z + c1.z + be1.z);
        o.w = g0 * (a0.w + a1.w + be0.w) + g1 * (c0.w + c1.w + be1.w);
        *(float4*)(y + (size_t)tok * Dm + col) = o;
    }
}

// ---------------- launch ----------------
extern "C" void kernel_launch(void* const* d_in, const int* in_sizes, int n_in,
                              void* d_out, int out_size, void* d_ws, size_t ws_size,
                              hipStream_t stream) {
    const float* x  = (const float*)d_in[0];
    const float* wg = (const float*)d_in[1];
    const float* W1 = (const float*)d_in[2];
    const float* b1 = (const float*)d_in[3];
    const float* W2 = (const float*)d_in[4];
    const float* b2 = (const float*)d_in[5];
    float* y = (float*)d_out;

    char* ws = (char*)d_ws;
    int*   padded     = (int*)(ws + 32);
    int*   offsets    = (int*)(ws + 64);
    int*   list       = (int*)(ws + 1024);                  // 64KB
    int*   tokes      = (int*)(ws + 132096);                // 16KB
    float* tokgate    = (float*)(ws + 148480);              // 16KB
    int*   t2e        = (int*)(ws + 164864);                // 16KB
    unsigned short* xb = (unsigned short*)(ws + 262144);    // 3MB

    size_t base = (size_t)4 << 20;
    size_t osz  = (size_t)2 * OBROWS * Dm * sizeof(float);  // 31.5MB
    int C = 8;
    size_t wsz = 0, hsz = 0;
    for (int c = 1; c <= 8; c <<= 1) {
        wsz = (size_t)NE * (Hh / c) * Dm * 2;
        hsz = (size_t)OBROWS * (Hh / c) * 2;
        size_t need = base + 2 * wsz + hsz + ((c == 1) ? 0 : osz);  // C=1: obuf overlays w1t
        C = c;
        if (need <= ws_size) break;
    }
    int Hc = Hh / C;
    wsz = (size_t)NE * Hc * Dm * 2;
    hsz = (size_t)OBROWS * Hc * 2;
    unsigned short* w1t  = (unsigned short*)(ws + base);
    unsigned short* w2t  = (unsigned short*)(ws + base + wsz);
    unsigned short* hbuf = (unsigned short*)(ws + base + 2 * wsz);
    float* obuf = (C == 1) ? (float*)w1t : (float*)(ws + base + 2 * wsz + hsz);

    const int MT = 16;                       // max 128-row tiles per expert
    int nT1 = (Hc / 64) * (Dm / 64) * NE;    // W1 transpose tiles (chunk 0)
    int nT2 = (Dm / 64) * (Hc / 64) * NE;    // W2 transpose tiles (chunk 0)
    int nG1 = (Hc / 128) * MT * NE;          // gemm1 blocks

    // W2T split: first nTa tiles ride in the assign dispatch (fills its 1-block
    // serialization bubble with streaming), the rest stay interleaved in gemm1.
    int nTa = (nT2 < 2048) ? nT2 : 2048;
    int nTr = nT2 - nTa;

    // prep: logits + chunk-0 W1 transpose
    prep_kernel<<<Btok / 4 + nT1, 256, 0, stream>>>(
        x, wg, t2e, tokgate, xb, W1, w1t, Hc, 0);
    // assign (block 0) + first nTa W2T tiles (blocks 1..nTa)
    assign_kernel<<<1 + nTa, 1024, 0, stream>>>(t2e, tokgate, padded, offsets, list, tokes,
                                                y + (size_t)Btok * Dm, W2, w2t, Hc);

    for (int c = 0; c < C; ++c) {
        if (c > 0) {
            transpose_kernel<<<dim3(Hc / 64, Dm / 64, NE), 256, 0, stream>>>(
                W1, w1t, Hh, Dm, (size_t)Dm * Hh, (size_t)Hc * Dm, 0, c * Hc);
            transpose_kernel<<<dim3(Dm / 64, Hc / 64, NE), 256, 0, stream>>>(
                W2, w2t, Dm, Hc, (size_t)Hh * Dm, (size_t)Dm * Hc, c * Hc, 0);
        }
        // gemm1 + (chunk 0 only) remaining W2 transpose tiles, Bresenham-interleaved
        int extra = (c == 0) ? nTr : 0;
        gemm1_kernel<<<nG1 + extra, 256, 0, stream>>>(
            xb, w1t, b1, list, padded, offsets, hbuf, Hc, c * Hc, nG1, extra, nTa, W2, w2t);
        // gemm2: N-tile 64, 12 nt x SK=2
        int nNT = Dm / 64;                   // 12
        gemm2_kernel<<<8 * MT * nNT * 2, 256, 0, stream>>>(
            hbuf, w2t, padded, offsets, obuf, Hc, MT, (c == 0) ? 0 : 1);
    }
    combine_kernel<<<Btok / 4, 256, 0, stream>>>(obuf, offsets, tokes, tokgate, b2, y);
}

// Round 4
// 132.891 us; speedup vs baseline: 1.1413x; 1.1413x over previous
//
#include <hip/hip_runtime.h>
#include <math.h>

// ---- problem constants ----
#define Btok 2048
#define Dm   768
#define NE   8
#define Hh   3072
#define OBROWS 5120

typedef short short8 __attribute__((ext_vector_type(8)));
typedef float f32x4  __attribute__((ext_vector_type(4)));

__device__ __forceinline__ short f2bf(float f) {
    unsigned u = __builtin_bit_cast(unsigned, f);
    u += 0x7fffu + ((u >> 16) & 1u);   // round-to-nearest-even
    return (short)(u >> 16);
}

// GELU (exact erf form) via Abramowitz-Stegun 7.1.26: |erf err| <= 1.5e-7,
// ~12 VALU inst (HW v_exp_f32) vs libm erff's ~18+ — epilogue VALU reduction.
// Error is ~4 orders below hbuf's bf16 quantization.
__device__ __forceinline__ float gelu_exact(float v) {
    float s = v * 0.70710678118654752440f;
    float a = fabsf(s);
    float t = 1.0f / fmaf(0.3275911f, a, 1.0f);
    float p = t * fmaf(t, fmaf(t, fmaf(t, fmaf(t, 1.061405429f, -1.453152027f),
                                       1.421413741f), -0.284496736f), 0.254829592f);
    float er = 1.0f - p * __expf(-s * s);
    er = copysignf(er, s);
    return 0.5f * v * (1.0f + er);
}

// async global->LDS, 16B per lane; LDS dest = uniform base + lane*16
#define GLDS(gsrc, ldst)                                                           \
    __builtin_amdgcn_global_load_lds(                                              \
        (const __attribute__((address_space(1))) void*)(gsrc),                     \
        (__attribute__((address_space(3))) void*)(ldst),                           \
        16, 0, 0)

// ---------------- logits body: top-2 per token, gates, x->bf16 ----------------
__device__ __forceinline__ void logits_body(const float* __restrict__ x,
                                            const float* __restrict__ wg,
                                            int* __restrict__ t2e,
                                            float* __restrict__ tokgate,
                                            unsigned short* __restrict__ xb,
                                            int b) {
    int wv   = threadIdx.x >> 6;
    int lane = threadIdx.x & 63;
    int tok  = b * 4 + wv;

    const float* xr = x + (size_t)tok * Dm;
    float xv[12];
#pragma unroll
    for (int i = 0; i < 12; ++i) xv[i] = xr[lane + i * 64];

    unsigned short* xw = xb + (size_t)tok * Dm;
#pragma unroll
    for (int i = 0; i < 12; ++i) xw[lane + i * 64] = (unsigned short)f2bf(xv[i]);

    float acc[NE];
#pragma unroll
    for (int e = 0; e < NE; ++e) acc[e] = 0.f;
#pragma unroll
    for (int i = 0; i < 12; ++i) {
        int d = lane + i * 64;
#pragma unroll
        for (int e = 0; e < NE; ++e) acc[e] += xv[i] * wg[d * NE + e];
    }
#pragma unroll
    for (int e = 0; e < NE; ++e) {
#pragma unroll
        for (int off = 32; off > 0; off >>= 1) acc[e] += __shfl_xor(acc[e], off);
    }

    if (lane == 0) {
        int i0 = 0; float v0 = acc[0];
#pragma unroll
        for (int e = 1; e < NE; ++e) { if (acc[e] > v0) { v0 = acc[e]; i0 = e; } }
        int i1 = -1; float v1 = -1e30f;
#pragma unroll
        for (int e = 0; e < NE; ++e) {
            if (e == i0) continue;
            if (acc[e] > v1) { v1 = acc[e]; i1 = e; }
        }
        float tt = __expf(v1 - v0);
        float g0 = 1.0f / (1.0f + tt);
        float g1 = 1.0f - g0;

        t2e[tok * 2 + 0]     = i0;
        t2e[tok * 2 + 1]     = i1;
        tokgate[tok * 2 + 0] = g0;
        tokgate[tok * 2 + 1] = g1;
    }
}

// ---------------- transpose body: fp32 [K][N] -> bf16 [N][K], 64x64 tile (256 thr) ----------------
__device__ __forceinline__ void transpose_body(float (*tile)[65],
                                               const float* __restrict__ in,
                                               unsigned short* __restrict__ out,
                                               int ldIn, int ldOut,
                                               size_t eStrideIn, size_t eStrideOut,
                                               int rowOff, int colOff,
                                               int bx, int by, int bz) {
    const float* src = in + (size_t)bz * eStrideIn
                     + (size_t)(rowOff + by * 64) * ldIn + colOff + bx * 64;
    unsigned short* dst = out + (size_t)bz * eStrideOut
                        + (size_t)(bx * 64) * ldOut + by * 64;
    int t = threadIdx.x;
    int r = t >> 4, c4 = (t & 15) * 4;
#pragma unroll
    for (int it = 0; it < 4; ++it) {
        float4 v = *(const float4*)(src + (size_t)(it * 16 + r) * ldIn + c4);
        tile[it * 16 + r][c4 + 0] = v.x;
        tile[it * 16 + r][c4 + 1] = v.y;
        tile[it * 16 + r][c4 + 2] = v.z;
        tile[it * 16 + r][c4 + 3] = v.w;
    }
    __syncthreads();
#pragma unroll
    for (int it = 0; it < 4; ++it) {
        int n = it * 16 + r;
        unsigned short o0 = (unsigned short)f2bf(tile[c4 + 0][n]);
        unsigned short o1 = (unsigned short)f2bf(tile[c4 + 1][n]);
        unsigned short o2 = (unsigned short)f2bf(tile[c4 + 2][n]);
        unsigned short o3 = (unsigned short)f2bf(tile[c4 + 3][n]);
        uint2 o;
        o.x = (unsigned)o0 | ((unsigned)o1 << 16);
        o.y = (unsigned)o2 | ((unsigned)o3 << 16);
        *(uint2*)(dst + (size_t)n * ldOut + c4) = o;
    }
}

// ---------------- transpose body for 1024-thread blocks: 1 ld / 1 st per thread ----------------
__device__ __forceinline__ void transpose_body_1k(float (*tile)[65],
                                                  const float* __restrict__ in,
                                                  unsigned short* __restrict__ out,
                                                  int ldIn, int ldOut,
                                                  size_t eStrideIn, size_t eStrideOut,
                                                  int rowOff, int colOff,
                                                  int bx, int by, int bz) {
    const float* src = in + (size_t)bz * eStrideIn
                     + (size_t)(rowOff + by * 64) * ldIn + colOff + bx * 64;
    unsigned short* dst = out + (size_t)bz * eStrideOut
                        + (size_t)(bx * 64) * ldOut + by * 64;
    int t = threadIdx.x;
    int r = t >> 4, c4 = (t & 15) * 4;
    float4 v = *(const float4*)(src + (size_t)r * ldIn + c4);
    tile[r][c4 + 0] = v.x;
    tile[r][c4 + 1] = v.y;
    tile[r][c4 + 2] = v.z;
    tile[r][c4 + 3] = v.w;
    __syncthreads();
    unsigned short o0 = (unsigned short)f2bf(tile[c4 + 0][r]);
    unsigned short o1 = (unsigned short)f2bf(tile[c4 + 1][r]);
    unsigned short o2 = (unsigned short)f2bf(tile[c4 + 2][r]);
    unsigned short o3 = (unsigned short)f2bf(tile[c4 + 3][r]);
    uint2 o;
    o.x = (unsigned)o0 | ((unsigned)o1 << 16);
    o.y = (unsigned)o2 | ((unsigned)o3 << 16);
    *(uint2*)(dst + (size_t)r * ldOut + c4) = o;
}

// standalone transpose (used for chunks c>0 when workspace is small)
__global__ __launch_bounds__(256)
void transpose_kernel(const float* __restrict__ in, unsigned short* __restrict__ out,
                      int ldIn, int ldOut, size_t eStrideIn, size_t eStrideOut,
                      int rowOff, int colOff) {
    __shared__ float tile[64][65];
    transpose_body(tile, in, out, ldIn, ldOut, eStrideIn, eStrideOut, rowOff, colOff,
                   blockIdx.x, blockIdx.y, blockIdx.z);
}

// ---------------- prep: blocks 0..511 = logits; rest = W1 transpose (chunk 0) ----------------
__global__ __launch_bounds__(256)
void prep_kernel(const float* __restrict__ x,
                 const float* __restrict__ wg,
                 int* __restrict__ t2e,
                 float* __restrict__ tokgate,
                 unsigned short* __restrict__ xb,
                 const float* __restrict__ W1, unsigned short* __restrict__ w1t,
                 int Hc, int colBase) {
    __shared__ float tile[64][65];
    int b = blockIdx.x;
    const int NL = Btok / 4;                 // 512 logits blocks

    if (b < NL) {
        logits_body(x, wg, t2e, tokgate, xb, b);
    } else {
        // W1 [e][d=768][h] -> w1t [e][h-local][d]
        int nx1 = Hc / 64, ny1 = Dm / 64;
        int q  = b - NL;
        int bx = q % nx1; q /= nx1;
        int by = q % ny1;
        int bz = q / ny1;
        transpose_body(tile, W1, w1t, Hh, Dm, (size_t)Dm * Hh, (size_t)Hc * Dm,
                       0, colBase, bx, by, bz);
    }
}

// ---------------- assign: block 0 = slots/offsets/loss/pad; blocks >0 = W2T tiles ----------------
__global__ __launch_bounds__(1024)
void assign_kernel(const int* __restrict__ t2e,
                   const float* __restrict__ tokgate,
                   int* __restrict__ padded,
                   int* __restrict__ offsets,
                   int* __restrict__ list,
                   int* __restrict__ tokes,
                   float* __restrict__ loss_out,
                   const float* __restrict__ W2,
                   unsigned short* __restrict__ w2t,
                   int Hc) {
    __shared__ int   scnt[NE];
    __shared__ int   spad[NE];
    __shared__ float simp[NE];
    __shared__ float tile[64][65];

    if (blockIdx.x > 0) {
        // W2 [e][h][d=768] -> w2t [e][d][h-local], chunk 0, tiles [0, nTa)
        int ti = blockIdx.x - 1;
        int nx2 = Dm / 64, ny2 = Hc / 64;
        int bx = ti % nx2; int q = ti / nx2;
        int by = q % ny2;
        int bz = q / ny2;
        transpose_body_1k(tile, W2, w2t, Dm, Hc, (size_t)Hh * Dm, (size_t)Dm * Hc,
                          0, 0, bx, by, bz);
        return;
    }

    int tid = threadIdx.x;
    if (tid < NE) { scnt[tid] = 0; simp[tid] = 0.f; }
    __syncthreads();

#pragma unroll
    for (int it = 0; it < Btok / 1024; ++it) {
        int tok = tid + it * 1024;
        int e0 = t2e[tok * 2], e1 = t2e[tok * 2 + 1];
        float g0 = tokgate[tok * 2], g1 = tokgate[tok * 2 + 1];
        int s0 = atomicAdd(&scnt[e0], 1);
        int s1 = atomicAdd(&scnt[e1], 1);
        list[e0 * Btok + s0] = tok;
        list[e1 * Btok + s1] = tok;
        tokes[tok * 2 + 0] = (e0 << 13) | s0;
        tokes[tok * 2 + 1] = (e1 << 13) | s1;
        atomicAdd(&simp[e0], g0);
        atomicAdd(&simp[e1], g1);
    }
    __syncthreads();

    if (tid == 0) {
        int off = 0;
        for (int e = 0; e < NE; ++e) {
            int p = (scnt[e] + 127) & ~127;
            spad[e]    = p;
            padded[e]  = p;
            offsets[e] = off;
            off += p;
        }
        float mi = 0.f, ml = 0.f;
        for (int e = 0; e < NE; ++e) { mi += simp[e]; ml += (float)scnt[e]; }
        mi *= (1.0f / NE); ml *= (1.0f / NE);
        float vi = 0.f, vl = 0.f;
        for (int e = 0; e < NE; ++e) {
            float di = simp[e] - mi;        vi += di * di;
            float dl = (float)scnt[e] - ml; vl += dl * dl;
        }
        vi /= (NE - 1); vl /= (NE - 1);
        loss_out[0] = 1e-2f * (vi / (mi * mi + 1e-10f) + vl / (ml * ml + 1e-10f));
    }
    __syncthreads();

    for (int e = 0; e < NE; ++e) {
        int c = scnt[e], p = spad[e];
        for (int s = c + tid; s < p; s += 1024) list[e * Btok + s] = 0;
    }
}

// ---------------- GEMM1 (+fused W2 transpose, Bresenham-interleaved block IDs) ----------------
__global__ __launch_bounds__(256)
void gemm1_kernel(const unsigned short* __restrict__ xb,
                  const unsigned short* __restrict__ w1t,  // [e][Hc][Dm] bf16
                  const float* __restrict__ b1,
                  const int* __restrict__ list,
                  const int* __restrict__ padded,
                  const int* __restrict__ offsets,
                  unsigned short* __restrict__ hbuf,       // [rows][Hc] bf16
                  int Hc, int colBase, int nG1, int nTr, int tixBase,
                  const float* __restrict__ W2,            // fused W2 transpose (chunk 0)
                  unsigned short* __restrict__ w2t) {
    __shared__ union __align__(16) {
        struct { unsigned short As[2][4096]; unsigned short Bs[2][4096]; } g;
        float tile[64][65];
    } sm;

    int b = blockIdx.x;
    int gid;
    if (nTr > 0) {
        int total = nG1 + nTr;
        int tc  = (int)(((long long)b * nTr) / total);
        int tc1 = (int)(((long long)(b + 1) * nTr) / total);
        if (tc1 != tc) {
            // W2 [e][h][d=768] -> w2t [e][d][h-local], chunk 0
            int tix = tixBase + tc;
            int nx2 = Dm / 64, ny2 = Hc / 64;
            int bx = tix % nx2; int q = tix / nx2;
            int by = q % ny2;
            int bz = q / ny2;
            transpose_body(sm.tile, W2, w2t, Dm, Hc, (size_t)Hh * Dm, (size_t)Dm * Hc,
                           0, 0, bx, by, bz);
            return;
        }
        gid = b - tc;
    } else {
        gid = b;
    }

    int NTQ = Hc / 128;
    int nt = gid % NTQ;
    int mt = (gid / NTQ) % 16;
    int e  = gid / (NTQ * 16);
    if (mt * 128 >= padded[e]) return;
    int roff = offsets[e];

    int t = threadIdx.x, w = t >> 6, lane = t & 63;
    int lr = lane & 15, lh = lane >> 4;
    int wr = (w >> 1) * 64, wc = (w & 1) * 64;
    int r0 = t >> 2;
    int ce = ((t & 3) ^ ((r0 >> 1) & 3)) * 8;   // pre-swizzled global k-chunk
    int ks = (lh ^ ((lr >> 1) & 3)) * 8;        // swizzled read k-chunk

    const int* lst = list + e * Btok + mt * 128;
    int tok0 = lst[r0], tok1 = lst[64 + r0];
    const unsigned short* pa0 = xb + (size_t)tok0 * Dm + ce;
    const unsigned short* pa1 = xb + (size_t)tok1 * Dm + ce;
    const unsigned short* wbp = w1t + ((size_t)e * Hc + (size_t)nt * 128) * Dm;
    const unsigned short* pb0 = wbp + (size_t)r0 * Dm + ce;
    const unsigned short* pb1 = wbp + (size_t)(64 + r0) * Dm + ce;

    int s0 = __builtin_amdgcn_readfirstlane(w * 1024);

    f32x4 acc[4][4];
#pragma unroll
    for (int i = 0; i < 4; ++i)
#pragma unroll
        for (int j = 0; j < 4; ++j) acc[i][j] = (f32x4){0.f, 0.f, 0.f, 0.f};

    auto stage = [&](int buf, int kb) {
        GLDS(pa0 + kb, (char*)&sm.g.As[buf][0] + s0);
        GLDS(pa1 + kb, (char*)&sm.g.As[buf][0] + s0 + 4096);
        GLDS(pb0 + kb, (char*)&sm.g.Bs[buf][0] + s0);
        GLDS(pb1 + kb, (char*)&sm.g.Bs[buf][0] + s0 + 4096);
    };
    auto compute = [&](int buf) {
        short8 a[4], bq[4];
#pragma unroll
        for (int i = 0; i < 4; ++i) a[i] = *(const short8*)&sm.g.As[buf][(wr + i * 16 + lr) * 32 + ks];
#pragma unroll
        for (int j = 0; j < 4; ++j) bq[j] = *(const short8*)&sm.g.Bs[buf][(wc + j * 16 + lr) * 32 + ks];
#pragma unroll
        for (int i = 0; i < 4; ++i)
#pragma unroll
            for (int j = 0; j < 4; ++j)
                acc[i][j] = __builtin_amdgcn_mfma_f32_16x16x32_bf16(a[i], bq[j], acc[i][j], 0, 0, 0);
    };

    const int NTK = Dm / 32;                       // 24
    stage(0, 0);
    __syncthreads();
    int cur = 0;
    for (int kt = 0; kt < NTK; ++kt) {
        if (kt + 1 < NTK) stage(cur ^ 1, (kt + 1) * 32);
        compute(cur);
        __syncthreads();
        cur ^= 1;
    }

    float bj[4];
#pragma unroll
    for (int j = 0; j < 4; ++j)
        bj[j] = b1[(size_t)e * Hh + colBase + nt * 128 + wc + j * 16 + lr];
#pragma unroll
    for (int i = 0; i < 4; ++i) {
#pragma unroll
        for (int j = 0; j < 4; ++j) {
#pragma unroll
            for (int r = 0; r < 4; ++r) {
                int row = wr + i * 16 + lh * 4 + r;
                float v = acc[i][j][r] + bj[j];
                v = gelu_exact(v);
                hbuf[(size_t)(roff + mt * 128 + row) * Hc + nt * 128 + wc + j * 16 + lr]
                    = (unsigned short)f2bf(v);
            }
        }
    }
}

// ---------------- GEMM2: obuf[sk] = h_rows @ W2t^T  (pinned 1-D grid, safe dbuf, SK=2) ----------------
// id = (((sk*6 + nt)*MT + mt) << 3) | e
__global__ __launch_bounds__(256)
void gemm2_kernel(const unsigned short* __restrict__ hbuf,
                  const unsigned short* __restrict__ w2t,  // [e][Dm][Hc] bf16
                  const int* __restrict__ padded,
                  const int* __restrict__ offsets,
                  float* __restrict__ obuf,                // [2][OBROWS][Dm] fp32
                  int Hc, int MT, int accum) {
    int id = blockIdx.x;
    int e  = id & 7;
    int rr = id >> 3;
    int mt = rr % MT; rr /= MT;
    int nt = rr % 6;
    int sk = rr / 6;
    if (mt * 128 >= padded[e]) return;
    int roff = offsets[e];
    int Kc = Hc >> 1, K0 = sk * Kc;

    __shared__ unsigned short As[2][4096];
    __shared__ unsigned short Bs[2][4096];

    int t = threadIdx.x, w = t >> 6, lane = t & 63;
    int lr = lane & 15, lh = lane >> 4;
    int wr = (w >> 1) * 64, wc = (w & 1) * 64;
    int r0 = t >> 2;
    int ce = ((t & 3) ^ ((r0 >> 1) & 3)) * 8;
    int ks = (lh ^ ((lr >> 1) & 3)) * 8;

    const unsigned short* ab  = hbuf + (size_t)(roff + mt * 128) * Hc + K0;
    const unsigned short* pa0 = ab + (size_t)r0 * Hc + ce;
    const unsigned short* pa1 = ab + (size_t)(64 + r0) * Hc + ce;
    const unsigned short* wbp = w2t + ((size_t)e * Dm + (size_t)nt * 128) * Hc + K0;
    const unsigned short* pb0 = wbp + (size_t)r0 * Hc + ce;
    const unsigned short* pb1 = wbp + (size_t)(64 + r0) * Hc + ce;

    int s0 = __builtin_amdgcn_readfirstlane(w * 1024);

    f32x4 acc[4][4];
#pragma unroll
    for (int i = 0; i < 4; ++i)
#pragma unroll
        for (int j = 0; j < 4; ++j) acc[i][j] = (f32x4){0.f, 0.f, 0.f, 0.f};

    auto stage = [&](int buf, int kb) {
        GLDS(pa0 + kb, (char*)&As[buf][0] + s0);
        GLDS(pa1 + kb, (char*)&As[buf][0] + s0 + 4096);
        GLDS(pb0 + kb, (char*)&Bs[buf][0] + s0);
        GLDS(pb1 + kb, (char*)&Bs[buf][0] + s0 + 4096);
    };
    auto compute = [&](int buf) {
        short8 a[4], bq[4];
#pragma unroll
        for (int i = 0; i < 4; ++i) a[i] = *(const short8*)&As[buf][(wr + i * 16 + lr) * 32 + ks];
#pragma unroll
        for (int j = 0; j < 4; ++j) bq[j] = *(const short8*)&Bs[buf][(wc + j * 16 + lr) * 32 + ks];
#pragma unroll
        for (int i = 0; i < 4; ++i)
#pragma unroll
            for (int j = 0; j < 4; ++j)
                acc[i][j] = __builtin_amdgcn_mfma_f32_16x16x32_bf16(a[i], bq[j], acc[i][j], 0, 0, 0);
    };

    const int NTK = Kc / 32;
    stage(0, 0);
    __syncthreads();
    int cur = 0;
    for (int kt = 0; kt < NTK; ++kt) {
        if (kt + 1 < NTK) stage(cur ^ 1, (kt + 1) * 32);
        compute(cur);
        __syncthreads();
        cur ^= 1;
    }

    float* orow = obuf + (size_t)sk * OBROWS * Dm
                + (size_t)(roff + mt * 128) * Dm + nt * 128;
#pragma unroll
    for (int i = 0; i < 4; ++i) {
#pragma unroll
        for (int r = 0; r < 4; ++r) {
            int row = wr + i * 16 + lh * 4 + r;
#pragma unroll
            for (int j = 0; j < 4; ++j) {
                int col = wc + j * 16 + lr;
                float v = acc[i][j][r];
                if (accum) v += orow[(size_t)row * Dm + col];
                orow[(size_t)row * Dm + col] = v;
            }
        }
    }
}

// ---------------- combine: y[tok] = sum_j g_j * (partials + b2[e_j]) ----------------
__global__ __launch_bounds__(256)
void combine_kernel(const float* __restrict__ obuf,
                    const int* __restrict__ offsets,
                    const int* __restrict__ tokes,
                    const float* __restrict__ tokgate,
                    const float* __restrict__ b2,
                    float* __restrict__ y) {
    int wv = threadIdx.x >> 6, lane = threadIdx.x & 63;
    int tok = blockIdx.x * 4 + wv;
    int p0 = tokes[tok * 2], p1 = tokes[tok * 2 + 1];
    float g0 = tokgate[tok * 2], g1 = tokgate[tok * 2 + 1];
    int e0 = p0 >> 13, ss0 = p0 & 8191;
    int e1 = p1 >> 13, ss1 = p1 & 8191;
    size_t r0 = (size_t)(offsets[e0] + ss0) * Dm;
    size_t r1 = (size_t)(offsets[e1] + ss1) * Dm;
    const size_t SLAB = (size_t)OBROWS * Dm;
#pragma unroll
    for (int i = 0; i < 3; ++i) {
        int col = (lane + i * 64) * 4;
        float4 a0 = *(const float4*)(obuf + r0 + col);
        float4 a1 = *(const float4*)(obuf + SLAB + r0 + col);
        float4 c0 = *(const float4*)(obuf + r1 + col);
        float4 c1 = *(const float4*)(obuf + SLAB + r1 + col);
        float4 be0 = *(const float4*)(b2 + (size_t)e0 * Dm + col);
        float4 be1 = *(const float4*)(b2 + (size_t)e1 * Dm + col);
        float4 o;
        o.x = g0 * (a0.x + a1.x + be0.x) + g1 * (c0.x + c1.x + be1.x);
        o.y = g0 * (a0.y + a1.y + be0.y) + g1 * (c0.y + c1.y + be1.y);
        o.z = g0 * (a0.z + a1.z + be0.z) + g1 * (c0.z + c1.z + be1.z);
        o.w = g0 * (a0.w + a1.w + be0.w) + g1 * (c0.w + c1.w + be1.w);
        *(float4*)(y + (size_t)tok * Dm + col) = o;
    }
}

// ---------------- launch ----------------
extern "C" void kernel_launch(void* const* d_in, const int* in_sizes, int n_in,
                              void* d_out, int out_size, void* d_ws, size_t ws_size,
                              hipStream_t stream) {
    const float* x  = (const float*)d_in[0];
    const float* wg = (const float*)d_in[1];
    const float* W1 = (const float*)d_in[2];
    const float* b1 = (const float*)d_in[3];
    const float* W2 = (const float*)d_in[4];
    const float* b2 = (const float*)d_in[5];
    float* y = (float*)d_out;

    char* ws = (char*)d_ws;
    int*   padded     = (int*)(ws + 32);
    int*   offsets    = (int*)(ws + 64);
    int*   list       = (int*)(ws + 1024);                  // 64KB
    int*   tokes      = (int*)(ws + 132096);                // 16KB
    float* tokgate    = (float*)(ws + 148480);              // 16KB
    int*   t2e        = (int*)(ws + 164864);                // 16KB
    unsigned short* xb = (unsigned short*)(ws + 262144);    // 3MB

    size_t base = (size_t)4 << 20;
    size_t osz  = (size_t)2 * OBROWS * Dm * sizeof(float);  // 31.5MB
    int C = 8;
    size_t wsz = 0, hsz = 0;
    for (int c = 1; c <= 8; c <<= 1) {
        wsz = (size_t)NE * (Hh / c) * Dm * 2;
        hsz = (size_t)OBROWS * (Hh / c) * 2;
        size_t need = base + 2 * wsz + hsz + ((c == 1) ? 0 : osz);  // C=1: obuf overlays w1t
        C = c;
        if (need <= ws_size) break;
    }
    int Hc = Hh / C;
    wsz = (size_t)NE * Hc * Dm * 2;
    hsz = (size_t)OBROWS * Hc * 2;
    unsigned short* w1t  = (unsigned short*)(ws + base);
    unsigned short* w2t  = (unsigned short*)(ws + base + wsz);
    unsigned short* hbuf = (unsigned short*)(ws + base + 2 * wsz);
    float* obuf = (C == 1) ? (float*)w1t : (float*)(ws + base + 2 * wsz + hsz);

    const int MT = 16;                       // max 128-row tiles per expert
    int nT1 = (Hc / 64) * (Dm / 64) * NE;    // W1 transpose tiles (chunk 0)
    int nT2 = (Dm / 64) * (Hc / 64) * NE;    // W2 transpose tiles (chunk 0)
    int nG1 = (Hc / 128) * MT * NE;          // gemm1 blocks

    // W2T split: first nTa tiles ride in the assign dispatch (fills its 1-block
    // serialization bubble with streaming), the rest stay interleaved in gemm1.
    int nTa = (nT2 < 2048) ? nT2 : 2048;
    int nTr = nT2 - nTa;

    // prep: logits + chunk-0 W1 transpose
    prep_kernel<<<Btok / 4 + nT1, 256, 0, stream>>>(
        x, wg, t2e, tokgate, xb, W1, w1t, Hc, 0);
    // assign (block 0) + first nTa W2T tiles (blocks 1..nTa)
    assign_kernel<<<1 + nTa, 1024, 0, stream>>>(t2e, tokgate, padded, offsets, list, tokes,
                                                y + (size_t)Btok * Dm, W2, w2t, Hc);

    for (int c = 0; c < C; ++c) {
        if (c > 0) {
            transpose_kernel<<<dim3(Hc / 64, Dm / 64, NE), 256, 0, stream>>>(
                W1, w1t, Hh, Dm, (size_t)Dm * Hh, (size_t)Hc * Dm, 0, c * Hc);
            transpose_kernel<<<dim3(Dm / 64, Hc / 64, NE), 256, 0, stream>>>(
                W2, w2t, Dm, Hc, (size_t)Hh * Dm, (size_t)Dm * Hc, c * Hc, 0);
        }
        // gemm1 + (chunk 0 only) remaining W2 transpose tiles, Bresenham-interleaved
        int extra = (c == 0) ? nTr : 0;
        gemm1_kernel<<<nG1 + extra, 256, 0, stream>>>(
            xb, w1t, b1, list, padded, offsets, hbuf, Hc, c * Hc, nG1, extra, nTa, W2, w2t);
        gemm2_kernel<<<8 * MT * 6 * 2, 256, 0, stream>>>(
            hbuf, w2t, padded, offsets, obuf, Hc, MT, (c == 0) ? 0 : 1);
    }
    combine_kernel<<<Btok / 4, 256, 0, stream>>>(obuf, offsets, tokes, tokgate, b2, y);
}